// Round 1
// baseline (550.600 us; speedup 1.0000x reference)
//
#include <hip/hip_runtime.h>
#include <stdint.h>

#define NB8   32768            // 262144 / 8 graphs per wave-iter
#define ALPHA 0.2f
#define NEGV  -9000000000000000.0f

__device__ __forceinline__ uint32_t bf16rne(float f) {
    uint32_t u = __float_as_uint(f);
    return (u + 0x7FFFu + ((u >> 16) & 1u)) >> 16;
}

// ---------------- precompute: Wc = W2@W1@W0, bc = W2@(W1@b0+b1)+b2 ----------------
__global__ __launch_bounds__(256) void gat_pre(
    const float* __restrict__ W0, const float* __restrict__ b0,
    const float* __restrict__ W1, const float* __restrict__ b1,
    const float* __restrict__ W2, const float* __restrict__ b2,
    float* __restrict__ wc, float* __restrict__ bc)
{
    __shared__ float T[64 * 64];
    __shared__ float tb[64];
    const int t = threadIdx.x;
    // T = W1 @ W0
    for (int s = 0; s < 16; ++s) {
        int idx = t + 256 * s;
        int i = idx >> 6, j = idx & 63;
        float acc = 0.f;
        for (int k = 0; k < 64; ++k) acc = fmaf(W1[i * 64 + k], W0[k * 64 + j], acc);
        T[idx] = acc;
    }
    if (t < 64) {
        float acc = b1[t];
        for (int k = 0; k < 64; ++k) acc = fmaf(W1[t * 64 + k], b0[k], acc);
        tb[t] = acc;
    }
    __syncthreads();
    // Wc = W2 @ T ; bc = W2 @ tb + b2
    for (int s = 0; s < 16; ++s) {
        int idx = t + 256 * s;
        int i = idx >> 6, j = idx & 63;
        float acc = 0.f;
        for (int k = 0; k < 64; ++k) acc = fmaf(W2[i * 64 + k], T[k * 64 + j], acc);
        wc[idx] = acc;
    }
    if (t < 64) {
        float acc = b2[t];
        for (int k = 0; k < 64; ++k) acc = fmaf(W2[t * 64 + k], tb[k], acc);
        bc[t] = acc;
    }
}

// ---------------- main fused kernel ----------------
// 1 wave handles 8 graphs (48 rows) per iteration. lane = output channel.
// LDS tile rows are quad-XOR-swizzled: logical quad q of row j lives at phys
// quad (q ^ (j&15)). byte addr = (j*256 + 16*(j&15)) ^ (16*q)  (bits disjoint).
// Per-float: byte = (j*256 + 4*lane) ^ (16*(j&15)).
__global__ __launch_bounds__(256, 2) void gat_main(
    const float* __restrict__ node, const int* __restrict__ adj,
    const float* __restrict__ a,
    const float* __restrict__ wc, const float* __restrict__ bc,
    float* __restrict__ out)
{
    __shared__ float    tile[4][48 * 64];   // 49152 B, per-wave node->x (in place)
    __shared__ float    ebuf[4][8][8];      // 1024 B, e_dst per (graph,row)
    __shared__ uint32_t pbuf[4][48][4];     // 3072 B, softmax rows packed bf16
    __shared__ float    a_sh[128];          // 512 B,  a_src | a_dst

    const int tid  = threadIdx.x;
    const int w    = tid >> 6;
    const int lane = tid & 63;

    // stage a (each wave writes the same values - benign duplicate)
    if (lane < 32) {
        float4 v = *(const float4*)(a + lane * 4);
        *(float4*)(a_sh + lane * 4) = v;
    }

    // adjacency bitmask (uniform -> scalarized)
    uint64_t amask = 0ull;
    #pragma unroll 1
    for (int ij = 0; ij < 36; ++ij) amask |= ((uint64_t)(adj[ij] & 1)) << ij;

    // this lane's row of Wc, and its bias
    float4 wq[16];
    #pragma unroll
    for (int q = 0; q < 16; ++q) wq[q] = *(const float4*)(wc + lane * 64 + q * 4);
    const float bias = bc[lane];

    char* const myt = (char*)&tile[w][0];
    asm volatile("s_waitcnt lgkmcnt(0)" ::: "memory");

    const int nwaves = (int)((gridDim.x * blockDim.x) >> 6);
    const int wgid   = (int)((blockIdx.x * blockDim.x + tid) >> 6);

    for (int g = wgid; g < NB8; g += nwaves) {
        const float* src = node + (size_t)g * 3072;

        // ---- P0: stage 8 graphs (768 quads, 12/lane), swizzled ----
        #pragma unroll
        for (int m = 0; m < 12; ++m) {
            int gq = lane + (m << 6);
            int j = gq >> 4, k4 = gq & 15;
            float4 v = *(const float4*)(src + gq * 4);
            *(float4*)(myt + ((j << 8) + ((k4 ^ (j & 15)) << 4))) = v;
        }
        asm volatile("s_waitcnt lgkmcnt(0)" ::: "memory");

        // ---- P1: x[j][lane] = node[j] . Wc[lane] + bias, written in place ----
        #pragma unroll 4
        for (int j = 0; j < 48; ++j) {
            const int ub = (j << 8) + ((j & 15) << 4);
            float ax = 0.f, ay = 0.f, az = 0.f, aw2 = 0.f;
            #pragma unroll
            for (int q = 0; q < 16; ++q) {
                float4 nv = *(const float4*)(myt + (ub ^ (q << 4)));
                ax  = fmaf(nv.x, wq[q].x, ax);
                ay  = fmaf(nv.y, wq[q].y, ay);
                az  = fmaf(nv.z, wq[q].z, az);
                aw2 = fmaf(nv.w, wq[q].w, aw2);
            }
            float xv = bias + ((ax + ay) + (az + aw2));
            // same-wave DS in-order: reads of row j precede this write
            *(float*)(myt + (((j << 8) + (lane << 2)) ^ ((j & 15) << 4))) = xv;
        }
        asm volatile("s_waitcnt lgkmcnt(0)" ::: "memory");

        // ---- P2: e_src/e_dst per row (lane = row, 48 active) ----
        float es = 0.f;
        if (lane < 48) {
            const int ub = (lane << 8) + ((lane & 15) << 4);
            float e0 = 0.f, e1 = 0.f, d0 = 0.f, d1 = 0.f;
            #pragma unroll
            for (int q = 0; q < 16; ++q) {
                float4 xv = *(const float4*)(myt + (ub ^ (q << 4)));
                float4 as = *(const float4*)(a_sh + 4 * q);
                float4 ad = *(const float4*)(a_sh + 64 + 4 * q);
                e0 = fmaf(xv.x, as.x, e0); e1 = fmaf(xv.y, as.y, e1);
                e0 = fmaf(xv.z, as.z, e0); e1 = fmaf(xv.w, as.w, e1);
                d0 = fmaf(xv.x, ad.x, d0); d1 = fmaf(xv.y, ad.y, d1);
                d0 = fmaf(xv.z, ad.z, d0); d1 = fmaf(xv.w, ad.w, d1);
            }
            es = e0 + e1;
            float ed = d0 + d1;
            ebuf[w][lane / 6][lane % 6] = ed;
        }
        asm volatile("s_waitcnt lgkmcnt(0)" ::: "memory");

        // ---- P3: masked softmax per row (lane = row), p -> bf16 LDS ----
        if (lane < 48) {
            const int bb = lane / 6;
            const int i  = lane - 6 * bb;
            const float* eb = &ebuf[w][bb][0];
            uint32_t rm = (uint32_t)((amask >> (i * 6)) & 63u);
            float l[6];
            #pragma unroll
            for (int j = 0; j < 6; ++j) {
                float z  = es + eb[j];
                float lk = fmaxf(z, ALPHA * z);          // leaky relu
                l[j] = (rm & (1u << j)) ? lk : NEGV;
            }
            float mm = fmaxf(fmaxf(fmaxf(l[0], l[1]), fmaxf(l[2], l[3])), fmaxf(l[4], l[5]));
            float p[6]; float sum = 0.f;
            #pragma unroll
            for (int j = 0; j < 6; ++j) { p[j] = __expf(l[j] - mm); sum += p[j]; }
            float inv = 1.0f / sum;
            uint4 pk;
            pk.x = bf16rne(p[0] * inv) | (bf16rne(p[1] * inv) << 16);
            pk.y = bf16rne(p[2] * inv) | (bf16rne(p[3] * inv) << 16);
            pk.z = bf16rne(p[4] * inv) | (bf16rne(p[5] * inv) << 16);
            pk.w = 0u;
            *(uint4*)&pbuf[w][lane][0] = pk;
        }
        asm volatile("s_waitcnt lgkmcnt(0)" ::: "memory");

        // ---- P4: out[i][lane] = sum_j p[i][j] * x[j][lane] ----
        const int lb = lane << 2;
        #pragma unroll 2
        for (int bb = 0; bb < 8; ++bb) {
            float xr[6];
            #pragma unroll
            for (int jj = 0; jj < 6; ++jj) {
                int rj = bb * 6 + jj;
                xr[jj] = *(const float*)(myt + (((rj << 8) + lb) ^ ((rj & 15) << 4)));
            }
            float* dst = out + ((size_t)(g * 8 + bb)) * 384 + lane;
            #pragma unroll
            for (int i2 = 0; i2 < 6; ++i2) {
                uint4 pu = *(const uint4*)&pbuf[w][bb * 6 + i2][0];
                float p0 = __uint_as_float(pu.x << 16);
                float p1 = __uint_as_float(pu.x & 0xFFFF0000u);
                float p2 = __uint_as_float(pu.y << 16);
                float p3 = __uint_as_float(pu.y & 0xFFFF0000u);
                float p4 = __uint_as_float(pu.z << 16);
                float p5 = __uint_as_float(pu.z & 0xFFFF0000u);
                float o = p0 * xr[0];
                o = fmaf(p1, xr[1], o);
                o = fmaf(p2, xr[2], o);
                o = fmaf(p3, xr[3], o);
                o = fmaf(p4, xr[4], o);
                o = fmaf(p5, xr[5], o);
                dst[i2 * 64] = o;
            }
        }
        asm volatile("s_waitcnt lgkmcnt(0)" ::: "memory");  // WAR vs next P0
    }
}

extern "C" void kernel_launch(void* const* d_in, const int* in_sizes, int n_in,
                              void* d_out, int out_size, void* d_ws, size_t ws_size,
                              hipStream_t stream)
{
    const float* node = (const float*)d_in[0];
    const int*   adj  = (const int*)d_in[1];
    const float* W0   = (const float*)d_in[2];
    const float* b0   = (const float*)d_in[3];
    const float* W1   = (const float*)d_in[4];
    const float* b1   = (const float*)d_in[5];
    const float* W2   = (const float*)d_in[6];
    const float* b2   = (const float*)d_in[7];
    const float* a    = (const float*)d_in[8];
    float* outp = (float*)d_out;
    float* wcb  = (float*)d_ws;                 // 4096 floats Wc + 64 floats bc

    gat_pre<<<1, 256, 0, stream>>>(W0, b0, W1, b1, W2, b2, wcb, wcb + 4096);
    gat_main<<<768, 256, 0, stream>>>(node, adj, a, wcb, wcb + 4096, outp);
}

// Round 3
// 349.880 us; speedup vs baseline: 1.5737x; 1.5737x over previous
//
#include <hip/hip_runtime.h>
#include <stdint.h>

typedef short v8s __attribute__((ext_vector_type(8)));
typedef float v4f __attribute__((ext_vector_type(4)));
typedef uint16_t u16;

#define NB8   32768            // 262144 / 8 graphs per wave-iter
#define ALPHA 0.2f
#define NEGV  -9000000000000000.0f

__device__ __forceinline__ uint32_t bf16rne(float f) {
    uint32_t u = __float_as_uint(f);
    return (u + 0x7FFFu + ((u >> 16) & 1u)) >> 16;
}
__device__ __forceinline__ uint32_t pk2(float lo, float hi) {
    return bf16rne(lo) | (bf16rne(hi) << 16);
}

// ---- precompute: Wc = W2@W1@W0 (bf16 out), bc = W2@(W1@b0+b1)+b2 ----
__global__ __launch_bounds__(256) void gat_pre(
    const float* __restrict__ W0, const float* __restrict__ b0,
    const float* __restrict__ W1, const float* __restrict__ b1,
    const float* __restrict__ W2, const float* __restrict__ b2,
    float* __restrict__ bc_out, u16* __restrict__ wcb16)
{
    __shared__ float T[64 * 64];
    __shared__ float tb[64];
    const int t = threadIdx.x;
    for (int s = 0; s < 16; ++s) {
        int idx = t + 256 * s; int i = idx >> 6, j = idx & 63;
        float acc = 0.f;
        for (int k = 0; k < 64; ++k) acc = fmaf(W1[i * 64 + k], W0[k * 64 + j], acc);
        T[idx] = acc;
    }
    if (t < 64) {
        float acc = b1[t];
        for (int k = 0; k < 64; ++k) acc = fmaf(W1[t * 64 + k], b0[k], acc);
        tb[t] = acc;
    }
    __syncthreads();
    for (int s = 0; s < 16; ++s) {
        int idx = t + 256 * s; int i = idx >> 6, j = idx & 63;
        float acc = 0.f;
        for (int k = 0; k < 64; ++k) acc = fmaf(W2[i * 64 + k], T[k * 64 + j], acc);
        wcb16[idx] = (u16)bf16rne(acc);
    }
    if (t < 64) {
        float acc = b2[t];
        for (int k = 0; k < 64; ++k) acc = fmaf(W2[t * 64 + k], tb[k], acc);
        bc_out[t] = acc;
    }
}

// ---- main: R1 skeleton (proven P2/P3/P4 + fences); P1 -> MFMA with direct
//      global A-fragment loads; D scattered f32 into R1's swizzled tile ----
__global__ __launch_bounds__(256, 3) void gat_main(
    const float* __restrict__ node, const int* __restrict__ adj,
    const float* __restrict__ a, const float* __restrict__ bc,
    const u16* __restrict__ wcb16, float* __restrict__ out)
{
    __shared__ float    tile[4][48 * 64];   // 49152 B, per-wave X (f32)
    __shared__ float    ebuf[4][8][8];      // 1024 B, e_dst per (graph,row)
    __shared__ uint32_t pbuf[4][48][4];     // 3072 B, softmax rows packed bf16
    __shared__ float    a_sh[128];          // 512 B,  a_src | a_dst

    const int tid  = threadIdx.x;
    const int w    = tid >> 6;
    const int lane = tid & 63;
    const int a_   = lane & 15;
    const int h    = lane >> 4;

    if (lane < 32) {
        float4 v = *(const float4*)(a + lane * 4);
        *(float4*)(a_sh + lane * 4) = v;
    }

    uint64_t amask = 0ull;
    #pragma unroll 1
    for (int ij = 0; ij < 36; ++ij) amask |= ((uint64_t)(adj[ij] & 1)) << ij;

    // B fragments: B[k=32kt+8h+j][col=16n+a_] = Wc[16n+a_][k]
    v8s Bw[4][2];
    #pragma unroll
    for (int n = 0; n < 4; ++n)
        #pragma unroll
        for (int kt = 0; kt < 2; ++kt)
            Bw[n][kt] = *(const v8s*)(wcb16 + (16 * n + a_) * 64 + 32 * kt + 8 * h);
    float bcl[4];
    #pragma unroll
    for (int n = 0; n < 4; ++n) bcl[n] = bc[16 * n + a_];

    char* const myt = (char*)&tile[w][0];
    asm volatile("s_waitcnt lgkmcnt(0)" ::: "memory");

    const int nwaves = (int)((gridDim.x * blockDim.x) >> 6);
    const int wgid   = (int)((blockIdx.x * blockDim.x + tid) >> 6);

    // preload first tile: lane holds node[row=16t+a_][k=32kt+8h .. +8] (f32)
    float4 Araw[3][2][2];
    {
        const char* nb = (const char*)node + (size_t)wgid * 12288 + a_ * 256 + h * 32;
        #pragma unroll
        for (int t = 0; t < 3; ++t) {
            const char* bt = nb + t * 4096;
            Araw[t][0][0] = *(const float4*)(bt);
            Araw[t][0][1] = *(const float4*)(bt + 16);
            Araw[t][1][0] = *(const float4*)(bt + 128);
            Araw[t][1][1] = *(const float4*)(bt + 144);
        }
    }

    #pragma unroll 1
    for (int g = wgid; g < NB8; g += nwaves) {
        // ---- pack A fragments (bf16, pure C rne) ----
        v8s A[3][2];
        #pragma unroll
        for (int t = 0; t < 3; ++t)
            #pragma unroll
            for (int kt = 0; kt < 2; ++kt) {
                union { uint32_t u[4]; v8s v; } f;
                f.u[0] = pk2(Araw[t][kt][0].x, Araw[t][kt][0].y);
                f.u[1] = pk2(Araw[t][kt][0].z, Araw[t][kt][0].w);
                f.u[2] = pk2(Araw[t][kt][1].x, Araw[t][kt][1].y);
                f.u[3] = pk2(Araw[t][kt][1].z, Araw[t][kt][1].w);
                A[t][kt] = f.v;
            }
        // ---- prefetch next tile ----
        {
            int gn = g + nwaves; if (gn >= NB8) gn = g;
            const char* nb = (const char*)node + (size_t)gn * 12288 + a_ * 256 + h * 32;
            #pragma unroll
            for (int t = 0; t < 3; ++t) {
                const char* bt = nb + t * 4096;
                Araw[t][0][0] = *(const float4*)(bt);
                Araw[t][0][1] = *(const float4*)(bt + 16);
                Araw[t][1][0] = *(const float4*)(bt + 128);
                Araw[t][1][1] = *(const float4*)(bt + 144);
            }
        }

        // ---- P1: X = node@Wc^T + bc via MFMA; D[row=16t+4h+r][col=16n+a_] ----
        #pragma unroll
        for (int t = 0; t < 3; ++t) {
            #pragma unroll
            for (int n = 0; n < 4; ++n) {
                v4f acc = { bcl[n], bcl[n], bcl[n], bcl[n] };
                acc = __builtin_amdgcn_mfma_f32_16x16x32_bf16(A[t][0], Bw[n][0], acc, 0, 0, 0);
                acc = __builtin_amdgcn_mfma_f32_16x16x32_bf16(A[t][1], Bw[n][1], acc, 0, 0, 0);
                const int col = 16 * n + a_;
                #pragma unroll
                for (int r = 0; r < 4; ++r) {
                    const int row = 16 * t + 4 * h + r;
                    *(float*)(myt + (((row << 8) + (col << 2)) ^ ((row & 15) << 4))) = acc[r];
                }
            }
        }
        asm volatile("s_waitcnt lgkmcnt(0)" ::: "memory");
        __builtin_amdgcn_sched_barrier(0);

        // ---- P2: e_src/e_dst per row (lane = row, 48 active) — R1 exact ----
        float es = 0.f;
        if (lane < 48) {
            const int ub = (lane << 8) + ((lane & 15) << 4);
            float e0 = 0.f, e1 = 0.f, d0 = 0.f, d1 = 0.f;
            #pragma unroll
            for (int q = 0; q < 16; ++q) {
                float4 xv = *(const float4*)(myt + (ub ^ (q << 4)));
                float4 as = *(const float4*)(a_sh + 4 * q);
                float4 ad = *(const float4*)(a_sh + 64 + 4 * q);
                e0 = fmaf(xv.x, as.x, e0); e1 = fmaf(xv.y, as.y, e1);
                e0 = fmaf(xv.z, as.z, e0); e1 = fmaf(xv.w, as.w, e1);
                d0 = fmaf(xv.x, ad.x, d0); d1 = fmaf(xv.y, ad.y, d1);
                d0 = fmaf(xv.z, ad.z, d0); d1 = fmaf(xv.w, ad.w, d1);
            }
            es = e0 + e1;
            float ed = d0 + d1;
            ebuf[w][lane / 6][lane % 6] = ed;
        }
        asm volatile("s_waitcnt lgkmcnt(0)" ::: "memory");
        __builtin_amdgcn_sched_barrier(0);

        // ---- P3: masked softmax per row — R1 exact ----
        if (lane < 48) {
            const int bb = lane / 6;
            const int i6 = lane - 6 * bb;
            const float* eb = &ebuf[w][bb][0];
            uint32_t rm = (uint32_t)((amask >> (i6 * 6)) & 63u);
            float l[6];
            #pragma unroll
            for (int j = 0; j < 6; ++j) {
                float z  = es + eb[j];
                float lk = fmaxf(z, ALPHA * z);
                l[j] = (rm & (1u << j)) ? lk : NEGV;
            }
            float mm = fmaxf(fmaxf(fmaxf(l[0], l[1]), fmaxf(l[2], l[3])), fmaxf(l[4], l[5]));
            float p[6]; float sum = 0.f;
            #pragma unroll
            for (int j = 0; j < 6; ++j) { p[j] = __expf(l[j] - mm); sum += p[j]; }
            float inv = 1.0f / sum;
            uint4 pk;
            pk.x = pk2(p[0] * inv, p[1] * inv);
            pk.y = pk2(p[2] * inv, p[3] * inv);
            pk.z = pk2(p[4] * inv, p[5] * inv);
            pk.w = 0u;
            *(uint4*)&pbuf[w][lane][0] = pk;
        }
        asm volatile("s_waitcnt lgkmcnt(0)" ::: "memory");
        __builtin_amdgcn_sched_barrier(0);

        // ---- P4: out[i][lane] = sum_j p[i][j] * x[j][lane] — R1 exact ----
        const int lb = lane << 2;
        #pragma unroll 2
        for (int bb = 0; bb < 8; ++bb) {
            float xr[6];
            #pragma unroll
            for (int jj = 0; jj < 6; ++jj) {
                int rj = bb * 6 + jj;
                xr[jj] = *(const float*)(myt + (((rj << 8) + lb) ^ ((rj & 15) << 4)));
            }
            float* dst = out + ((size_t)(g * 8 + bb)) * 384 + lane;
            #pragma unroll
            for (int i2 = 0; i2 < 6; ++i2) {
                uint4 pu = *(const uint4*)&pbuf[w][bb * 6 + i2][0];
                float p0 = __uint_as_float(pu.x << 16);
                float p1 = __uint_as_float(pu.x & 0xFFFF0000u);
                float p2 = __uint_as_float(pu.y << 16);
                float p3 = __uint_as_float(pu.y & 0xFFFF0000u);
                float p4 = __uint_as_float(pu.z << 16);
                float p5 = __uint_as_float(pu.z & 0xFFFF0000u);
                float o = p0 * xr[0];
                o = fmaf(p1, xr[1], o);
                o = fmaf(p2, xr[2], o);
                o = fmaf(p3, xr[3], o);
                o = fmaf(p4, xr[4], o);
                o = fmaf(p5, xr[5], o);
                dst[i2 * 64] = o;
            }
        }
        asm volatile("s_waitcnt lgkmcnt(0)" ::: "memory");  // WAR vs next P1
        __builtin_amdgcn_sched_barrier(0);
    }
}

extern "C" void kernel_launch(void* const* d_in, const int* in_sizes, int n_in,
                              void* d_out, int out_size, void* d_ws, size_t ws_size,
                              hipStream_t stream)
{
    const float* node = (const float*)d_in[0];
    const int*   adj  = (const int*)d_in[1];
    const float* W0   = (const float*)d_in[2];
    const float* b0   = (const float*)d_in[3];
    const float* W1   = (const float*)d_in[4];
    const float* b1   = (const float*)d_in[5];
    const float* W2   = (const float*)d_in[6];
    const float* b2   = (const float*)d_in[7];
    const float* a    = (const float*)d_in[8];
    float* outp = (float*)d_out;

    float* wsf   = (float*)d_ws;
    float* bcp   = wsf;                      // 64 f32
    u16*   wcb16 = (u16*)(wsf + 64);         // 4096 u16 (16B-aligned)

    gat_pre<<<1, 256, 0, stream>>>(W0, b0, W1, b1, W2, b2, bcp, wcb16);
    gat_main<<<768, 256, 0, stream>>>(node, adj, a, bcp, wcb16, outp);
}